// Round 14
// baseline (94.296 us; speedup 1.0000x reference)
//
#include <hip/hip_runtime.h>
#include <math.h>

#define NTOK 16384
#define D_   2048
#define E_   64
#define TPB  16            // tokens per block (16 real MFMA rows)
#define NKC  (D_/32)       // 64 k32-steps

typedef _Float16 f16x8 __attribute__((ext_vector_type(8)));
typedef float    f32x4 __attribute__((ext_vector_type(4)));

#define LSCALE      256.0f          // pre-scale x and W before f16 split (denorm guard)
#define LSCALE2_INV (1.0f/65536.0f) // exact pow2 un-scale of acc

// ---- Kernel 1: W (E x D fp32) -> fragment-ordered f16 hi/lo, scaled x256 ----
// Fragment order: element j of lane l for (n-tile nt, k32-step kc) is
//   W[e = nt*16 + (l&15)][k = kc*32 + (l>>4)*4 + (j&3) + (j>=4 ? 16 : 0)]
// Same k-map as the A operand -> any deviation from HW k-order cancels.
__global__ __launch_bounds__(256)
void prep_w(const float* __restrict__ W,
            _Float16* __restrict__ wh, _Float16* __restrict__ wl)
{
    const int idx = blockIdx.x * 256 + threadIdx.x;   // 0..16383
    const int l  = idx & 63;
    const int kc = (idx >> 6) & 63;
    const int nt = idx >> 12;                          // 0..3
    const int e  = nt * 16 + (l & 15);
    const int g  = l >> 4;
    const float* src = W + (size_t)e * D_ + kc * 32 + g * 4;
    const float4 f0 = *reinterpret_cast<const float4*>(src);
    const float4 f1 = *reinterpret_cast<const float4*>(src + 16);
    const float v[8] = {f0.x, f0.y, f0.z, f0.w, f1.x, f1.y, f1.z, f1.w};
    f16x8 h, lo;
#pragma unroll
    for (int j = 0; j < 8; ++j) {
        const float vs = v[j] * LSCALE;
        const _Float16 hj = (_Float16)vs;
        h[j]  = hj;
        lo[j] = (_Float16)(vs - (float)hj);
    }
    *reinterpret_cast<f16x8*>(wh + (size_t)idx * 8) = h;
    *reinterpret_cast<f16x8*>(wl + (size_t)idx * 8) = lo;
}

// ---- Kernel 2: MFMA router, expert-split waves ----
// 1024 blocks x 256 threads (4 waves). Wave w owns n-tile nt=w (16 experts)
// for the block's 16 tokens -> each (token,expert) chain computed by exactly
// one wave with the FROZEN sequence (hh,lh,hl; kc ascending; same fragment
// maps) = bitwise-identical logits to rounds 5-13 (absmax 1.0; do NOT
// reorder / K-split / term-split).
// Rationale vs r12/r13: B traffic stays at r12's 512 MB (128 KB/wave) while
// TLP rises to 16 waves/CU = 4/SIMD (r12 had 1/SIMD; compiler-collapsed
// depth-4 ring covers only ~280 of ~900 cyc, so TLP must hide the rest).
// Zero barriers / zero LDS in the K-loop; branch-free steady state (s=15
// peeled so the unrolled body has no control flow to block load hoisting).
// Per-wave VGPR ~110 fits the 128 budget of (256,4) without ring collapse.
__global__ __launch_bounds__(256, 4)
void router_mfma(const float* __restrict__ x,
                 const _Float16* __restrict__ wh,
                 const _Float16* __restrict__ wl,
                 const float* __restrict__ bias,
                 float* __restrict__ out)
{
    __shared__ float smem[TPB * 65 + TPB * 4];   // logits [16][65] + res [16][4]

    const int tid = threadIdx.x;
    const int l   = tid & 63;
    const int w   = __builtin_amdgcn_readfirstlane(tid >> 6);  // nt = 0..3
    const int T0  = blockIdx.x * TPB;
    const int g   = l >> 4;

    const float* xp = x + (size_t)(T0 + (l & 15)) * D_ + g * 4;
    const _Float16* bh_b = wh + (size_t)w * 32768 + (size_t)l * 8;  // + kc*512
    const _Float16* bl_b = wl + (size_t)w * 32768 + (size_t)l * 8;

    f32x4 acc = {0.f, 0.f, 0.f, 0.f};

    float4 xa[4], xb[4];          // x ring, slot = kc&3 (static after unroll)
    f16x8  BH[4], BL[4];          // B ring (own nt only)

    // prologue: fill depth-4 ring (kc = 0..3)
#pragma unroll
    for (int j = 0; j < 4; ++j) {
        xa[j] = *reinterpret_cast<const float4*>(xp + j * 32);
        xb[j] = *reinterpret_cast<const float4*>(xp + j * 32 + 16);
        BH[j] = *reinterpret_cast<const f16x8*>(bh_b + j * 512);
        BL[j] = *reinterpret_cast<const f16x8*>(bl_b + j * 512);
    }

    // steady state: 15 supersteps of 4 kc, unconditional prefetch (branch-free)
    for (int s = 0; s < 15; ++s) {
        const int K = s << 2;
#pragma unroll
        for (int j = 0; j < 4; ++j) {
            f16x8 ah, al_;
            {
                float vs;
                vs = xa[j].x * LSCALE; ah[0] = (_Float16)vs; al_[0] = (_Float16)(vs - (float)ah[0]);
                vs = xa[j].y * LSCALE; ah[1] = (_Float16)vs; al_[1] = (_Float16)(vs - (float)ah[1]);
                vs = xa[j].z * LSCALE; ah[2] = (_Float16)vs; al_[2] = (_Float16)(vs - (float)ah[2]);
                vs = xa[j].w * LSCALE; ah[3] = (_Float16)vs; al_[3] = (_Float16)(vs - (float)ah[3]);
                vs = xb[j].x * LSCALE; ah[4] = (_Float16)vs; al_[4] = (_Float16)(vs - (float)ah[4]);
                vs = xb[j].y * LSCALE; ah[5] = (_Float16)vs; al_[5] = (_Float16)(vs - (float)ah[5]);
                vs = xb[j].z * LSCALE; ah[6] = (_Float16)vs; al_[6] = (_Float16)(vs - (float)ah[6]);
                vs = xb[j].w * LSCALE; ah[7] = (_Float16)vs; al_[7] = (_Float16)(vs - (float)ah[7]);
            }
            acc = __builtin_amdgcn_mfma_f32_16x16x32_f16(ah,  BH[j], acc, 0, 0, 0);
            acc = __builtin_amdgcn_mfma_f32_16x16x32_f16(al_, BH[j], acc, 0, 0, 0);
            acc = __builtin_amdgcn_mfma_f32_16x16x32_f16(ah,  BL[j], acc, 0, 0, 0);
            // refill the slot just consumed (kc+4); kn max = 14*4+3+4 = 63
            const int kn = K + j + 4;
            xa[j] = *reinterpret_cast<const float4*>(xp + kn * 32);
            xb[j] = *reinterpret_cast<const float4*>(xp + kn * 32 + 16);
            BH[j] = *reinterpret_cast<const f16x8*>(bh_b + (size_t)kn * 512);
            BL[j] = *reinterpret_cast<const f16x8*>(bl_b + (size_t)kn * 512);
        }
    }
    // peeled last superstep (kc 60..63): no prefetch
#pragma unroll
    for (int j = 0; j < 4; ++j) {
        f16x8 ah, al_;
        {
            float vs;
            vs = xa[j].x * LSCALE; ah[0] = (_Float16)vs; al_[0] = (_Float16)(vs - (float)ah[0]);
            vs = xa[j].y * LSCALE; ah[1] = (_Float16)vs; al_[1] = (_Float16)(vs - (float)ah[1]);
            vs = xa[j].z * LSCALE; ah[2] = (_Float16)vs; al_[2] = (_Float16)(vs - (float)ah[2]);
            vs = xa[j].w * LSCALE; ah[3] = (_Float16)vs; al_[3] = (_Float16)(vs - (float)ah[3]);
            vs = xb[j].x * LSCALE; ah[4] = (_Float16)vs; al_[4] = (_Float16)(vs - (float)ah[4]);
            vs = xb[j].y * LSCALE; ah[5] = (_Float16)vs; al_[5] = (_Float16)(vs - (float)ah[5]);
            vs = xb[j].z * LSCALE; ah[6] = (_Float16)vs; al_[6] = (_Float16)(vs - (float)ah[6]);
            vs = xb[j].w * LSCALE; ah[7] = (_Float16)vs; al_[7] = (_Float16)(vs - (float)ah[7]);
        }
        acc = __builtin_amdgcn_mfma_f32_16x16x32_f16(ah,  BH[j], acc, 0, 0, 0);
        acc = __builtin_amdgcn_mfma_f32_16x16x32_f16(al_, BH[j], acc, 0, 0, 0);
        acc = __builtin_amdgcn_mfma_f32_16x16x32_f16(ah,  BL[j], acc, 0, 0, 0);
    }

    // ---- C tile -> LDS logits. C layout: col = lane&15, row = (lane>>4)*4+r ----
    {
        const int col = w * 16 + (l & 15);
#pragma unroll
        for (int r = 0; r < 4; ++r) {
            const int t = g * 4 + r;                  // token 0..15
            smem[t * 65 + col] = acc[r] * LSCALE2_INV;
        }
    }
    __syncthreads();

    // ---- top-2 + 2-way softmax (frozen scan): thread t handles token t ----
    float* res = smem + TPB * 65;
    if (tid < TPB) {
        const float* lg = smem + tid * 65;
        float m1 = -INFINITY, m2 = -INFINITY;
        int i1 = 0, i2 = 0;
        for (int e = 0; e < E_; ++e) {
            const float v = lg[e] + bias[e];
            if (v > m1)      { m2 = m1; i2 = i1; m1 = v; i1 = e; }
            else if (v > m2) { m2 = v;  i2 = e; }
        }
        const float ex  = expf(m2 - m1);
        const float den = 1.f + ex;
        res[tid*4+0] = 1.f / den;
        res[tid*4+1] = ex / den;
        res[tid*4+2] = (float)i1;
        res[tid*4+3] = (float)i2;
    }
    __syncthreads();

    // ---- output: probs (16 tokens x 64 experts = 1024 floats), float4 ----
    float* ob = out + (size_t)T0 * E_;
    {
        const int idx = tid * 4;
        const int t   = idx >> 6;
        const int e0  = idx & 63;
        const float p1 = res[t*4+0];
        const float p2 = res[t*4+1];
        const int   i1 = (int)res[t*4+2];
        const int   i2 = (int)res[t*4+3];
        float4 v;
        v.x = (e0+0 == i1) ? p1 : ((e0+0 == i2) ? p2 : 0.f);
        v.y = (e0+1 == i1) ? p1 : ((e0+1 == i2) ? p2 : 0.f);
        v.z = (e0+2 == i1) ? p1 : ((e0+2 == i2) ? p2 : 0.f);
        v.w = (e0+3 == i1) ? p1 : ((e0+3 == i2) ? p2 : 0.f);
        *reinterpret_cast<float4*>(ob + idx) = v;
    }
    // ids as float values (whole d_out is read as float32)
    if (tid < TPB * 2) {
        out[(size_t)NTOK * E_ + (size_t)T0 * 2 + tid] =
            res[(tid >> 1) * 4 + 2 + (tid & 1)];
    }
}

extern "C" void kernel_launch(void* const* d_in, const int* in_sizes, int n_in,
                              void* d_out, int out_size, void* d_ws, size_t ws_size,
                              hipStream_t stream) {
    const float* x = (const float*)d_in[0];
    const float* W = (const float*)d_in[1];
    const float* b = (const float*)d_in[2];
    float* out     = (float*)d_out;
    _Float16* wh   = (_Float16*)d_ws;                       // 256 KB
    _Float16* wl   = wh + (size_t)4 * NKC * 64 * 8;         // +256 KB

    hipLaunchKernelGGL(prep_w, dim3(64), dim3(256), 0, stream, W, wh, wl);
    hipLaunchKernelGGL(router_mfma, dim3(NTOK / TPB), dim3(256), 0, stream,
                       x, wh, wl, b, out);
}

// Round 15
// 49.523 us; speedup vs baseline: 1.9041x; 1.9041x over previous
//
#include <hip/hip_runtime.h>
#include <math.h>

#define NTOK 16384
#define D_   2048
#define E_   64
#define TPB  16            // tokens per block (= per wave)
#define NKC  (D_/32)       // 64 k32-steps

typedef _Float16 f16x8 __attribute__((ext_vector_type(8)));
typedef float    f32x4 __attribute__((ext_vector_type(4)));

#define LSCALE      256.0f          // pre-scale x and W before f16 split (denorm guard)
#define LSCALE2_INV (1.0f/65536.0f) // exact pow2 un-scale of acc

// ---- Kernel 1: W (E x D fp32) -> fragment-ordered f16 hi/lo, scaled x256 ----
// Fragment order: element j of lane l for (n-tile nt, k32-step kc) is
//   W[e = nt*16 + (l&15)][k = kc*32 + (l>>4)*4 + (j&3) + (j>=4 ? 16 : 0)]
// Same k-map as the A operand -> any deviation from HW k-order cancels.
__global__ __launch_bounds__(256)
void prep_w(const float* __restrict__ W,
            _Float16* __restrict__ wh, _Float16* __restrict__ wl)
{
    const int idx = blockIdx.x * 256 + threadIdx.x;   // 0..16383
    const int l  = idx & 63;
    const int kc = (idx >> 6) & 63;
    const int nt = idx >> 12;                          // 0..3
    const int e  = nt * 16 + (l & 15);
    const int g  = l >> 4;
    const float* src = W + (size_t)e * D_ + kc * 32 + g * 4;
    const float4 f0 = *reinterpret_cast<const float4*>(src);
    const float4 f1 = *reinterpret_cast<const float4*>(src + 16);
    const float v[8] = {f0.x, f0.y, f0.z, f0.w, f1.x, f1.y, f1.z, f1.w};
    f16x8 h, lo;
#pragma unroll
    for (int j = 0; j < 8; ++j) {
        const float vs = v[j] * LSCALE;
        const _Float16 hj = (_Float16)vs;
        h[j]  = hj;
        lo[j] = (_Float16)(vs - (float)hj);
    }
    *reinterpret_cast<f16x8*>(wh + (size_t)idx * 8) = h;
    *reinterpret_cast<f16x8*>(wl + (size_t)idx * 8) = lo;
}

// ---- Kernel 2: MFMA router, single-wave blocks, PINNED depth-4 ring ----
// 1024 blocks x 64 threads (1 wave = 16 tokens x all 64 experts, 4 acc tiles).
// Identical to round 12 (best: 51.6 us) except ONE change: a
// sched_barrier(0) after each prefetch group. r12/r13/r14 all show hipcc
// sinking the ring prefetches to just before use (VGPR 112/108/52 vs the
// ~190 the ring needs), collapsing in-flight bytes to ~1KB/wave -> one full
// exposed memory latency per kc (measured ~2850 cyc/kc). The fence forces
// issue >= 3 kc-bodies before use. Ring indices static (rule #20).
// Per-C-tile MFMA chain (hh,lh,hl; kc ascending; same cvt, same fragment
// maps) is bitwise-identical to rounds 5-14 (absmax 1.0; do NOT reorder).
__global__ __launch_bounds__(64, 1)
void router_mfma(const float* __restrict__ x,
                 const _Float16* __restrict__ wh,
                 const _Float16* __restrict__ wl,
                 const float* __restrict__ bias,
                 float* __restrict__ out)
{
    __shared__ float smem[TPB * 65 + TPB * 4];   // logits [16][65] + res [16][4]

    const int l  = threadIdx.x;                  // 0..63, one wave
    const int T0 = blockIdx.x * TPB;
    const int g  = l >> 4;

    const float* xp = x + (size_t)(T0 + (l & 15)) * D_ + g * 4;
    const _Float16* bh_b = wh + (size_t)l * 8;   // + nt*32768 + kc*512
    const _Float16* bl_b = wl + (size_t)l * 8;

    f32x4 acc0 = {0.f,0.f,0.f,0.f}, acc1 = {0.f,0.f,0.f,0.f};
    f32x4 acc2 = {0.f,0.f,0.f,0.f}, acc3 = {0.f,0.f,0.f,0.f};

    float4 xa[4], xb[4];          // x ring, slot = kc&3 (static index after unroll)
    f16x8  BH[4][4], BL[4][4];    // B ring, [slot][nt]

    // prologue: fill depth-4 ring (kc = 0..3)
#pragma unroll
    for (int j = 0; j < 4; ++j) {
        xa[j] = *reinterpret_cast<const float4*>(xp + j * 32);
        xb[j] = *reinterpret_cast<const float4*>(xp + j * 32 + 16);
#pragma unroll
        for (int nt = 0; nt < 4; ++nt) {
            BH[j][nt] = *reinterpret_cast<const f16x8*>(bh_b + nt * 32768 + j * 512);
            BL[j][nt] = *reinterpret_cast<const f16x8*>(bl_b + nt * 32768 + j * 512);
        }
    }

    // steady state: s = 0..14, unconditional prefetch, fence-pinned
    for (int s = 0; s < 15; ++s) {
        const int K = s << 2;
#pragma unroll
        for (int j = 0; j < 4; ++j) {
            // cvt (frozen math)
            f16x8 ah, al_;
            {
                float vs;
                vs = xa[j].x * LSCALE; ah[0] = (_Float16)vs; al_[0] = (_Float16)(vs - (float)ah[0]);
                vs = xa[j].y * LSCALE; ah[1] = (_Float16)vs; al_[1] = (_Float16)(vs - (float)ah[1]);
                vs = xa[j].z * LSCALE; ah[2] = (_Float16)vs; al_[2] = (_Float16)(vs - (float)ah[2]);
                vs = xa[j].w * LSCALE; ah[3] = (_Float16)vs; al_[3] = (_Float16)(vs - (float)ah[3]);
                vs = xb[j].x * LSCALE; ah[4] = (_Float16)vs; al_[4] = (_Float16)(vs - (float)ah[4]);
                vs = xb[j].y * LSCALE; ah[5] = (_Float16)vs; al_[5] = (_Float16)(vs - (float)ah[5]);
                vs = xb[j].z * LSCALE; ah[6] = (_Float16)vs; al_[6] = (_Float16)(vs - (float)ah[6]);
                vs = xb[j].w * LSCALE; ah[7] = (_Float16)vs; al_[7] = (_Float16)(vs - (float)ah[7]);
            }
            // 12 MFMA: per-tile chain hh, lh, hl (frozen)
            acc0 = __builtin_amdgcn_mfma_f32_16x16x32_f16(ah,  BH[j][0], acc0, 0, 0, 0);
            acc0 = __builtin_amdgcn_mfma_f32_16x16x32_f16(al_, BH[j][0], acc0, 0, 0, 0);
            acc0 = __builtin_amdgcn_mfma_f32_16x16x32_f16(ah,  BL[j][0], acc0, 0, 0, 0);
            acc1 = __builtin_amdgcn_mfma_f32_16x16x32_f16(ah,  BH[j][1], acc1, 0, 0, 0);
            acc1 = __builtin_amdgcn_mfma_f32_16x16x32_f16(al_, BH[j][1], acc1, 0, 0, 0);
            acc1 = __builtin_amdgcn_mfma_f32_16x16x32_f16(ah,  BL[j][1], acc1, 0, 0, 0);
            acc2 = __builtin_amdgcn_mfma_f32_16x16x32_f16(ah,  BH[j][2], acc2, 0, 0, 0);
            acc2 = __builtin_amdgcn_mfma_f32_16x16x32_f16(al_, BH[j][2], acc2, 0, 0, 0);
            acc2 = __builtin_amdgcn_mfma_f32_16x16x32_f16(ah,  BL[j][2], acc2, 0, 0, 0);
            acc3 = __builtin_amdgcn_mfma_f32_16x16x32_f16(ah,  BH[j][3], acc3, 0, 0, 0);
            acc3 = __builtin_amdgcn_mfma_f32_16x16x32_f16(al_, BH[j][3], acc3, 0, 0, 0);
            acc3 = __builtin_amdgcn_mfma_f32_16x16x32_f16(ah,  BL[j][3], acc3, 0, 0, 0);
            // prefetch kc+4 into the slot just consumed (depth-4 ring)
            {
                const int kn = K + j + 4;
                xa[j] = *reinterpret_cast<const float4*>(xp + kn * 32);
                xb[j] = *reinterpret_cast<const float4*>(xp + kn * 32 + 16);
#pragma unroll
                for (int nt = 0; nt < 4; ++nt) {
                    BH[j][nt] = *reinterpret_cast<const f16x8*>(bh_b + nt * 32768 + (size_t)kn * 512);
                    BL[j][nt] = *reinterpret_cast<const f16x8*>(bl_b + nt * 32768 + (size_t)kn * 512);
                }
            }
            // PIN: prefetches may not sink below this point (the one change
            // vs round 12 -- defeats hipcc's load-sinking that collapsed the
            // ring to ~1KB in flight).
            __builtin_amdgcn_sched_barrier(0);
        }
    }
    // peeled last superstep (kc 60..63): no prefetch, no fences
#pragma unroll
    for (int j = 0; j < 4; ++j) {
        f16x8 ah, al_;
        {
            float vs;
            vs = xa[j].x * LSCALE; ah[0] = (_Float16)vs; al_[0] = (_Float16)(vs - (float)ah[0]);
            vs = xa[j].y * LSCALE; ah[1] = (_Float16)vs; al_[1] = (_Float16)(vs - (float)ah[1]);
            vs = xa[j].z * LSCALE; ah[2] = (_Float16)vs; al_[2] = (_Float16)(vs - (float)ah[2]);
            vs = xa[j].w * LSCALE; ah[3] = (_Float16)vs; al_[3] = (_Float16)(vs - (float)ah[3]);
            vs = xb[j].x * LSCALE; ah[4] = (_Float16)vs; al_[4] = (_Float16)(vs - (float)ah[4]);
            vs = xb[j].y * LSCALE; ah[5] = (_Float16)vs; al_[5] = (_Float16)(vs - (float)ah[5]);
            vs = xb[j].z * LSCALE; ah[6] = (_Float16)vs; al_[6] = (_Float16)(vs - (float)ah[6]);
            vs = xb[j].w * LSCALE; ah[7] = (_Float16)vs; al_[7] = (_Float16)(vs - (float)ah[7]);
        }
        acc0 = __builtin_amdgcn_mfma_f32_16x16x32_f16(ah,  BH[j][0], acc0, 0, 0, 0);
        acc0 = __builtin_amdgcn_mfma_f32_16x16x32_f16(al_, BH[j][0], acc0, 0, 0, 0);
        acc0 = __builtin_amdgcn_mfma_f32_16x16x32_f16(ah,  BL[j][0], acc0, 0, 0, 0);
        acc1 = __builtin_amdgcn_mfma_f32_16x16x32_f16(ah,  BH[j][1], acc1, 0, 0, 0);
        acc1 = __builtin_amdgcn_mfma_f32_16x16x32_f16(al_, BH[j][1], acc1, 0, 0, 0);
        acc1 = __builtin_amdgcn_mfma_f32_16x16x32_f16(ah,  BL[j][1], acc1, 0, 0, 0);
        acc2 = __builtin_amdgcn_mfma_f32_16x16x32_f16(ah,  BH[j][2], acc2, 0, 0, 0);
        acc2 = __builtin_amdgcn_mfma_f32_16x16x32_f16(al_, BH[j][2], acc2, 0, 0, 0);
        acc2 = __builtin_amdgcn_mfma_f32_16x16x32_f16(ah,  BL[j][2], acc2, 0, 0, 0);
        acc3 = __builtin_amdgcn_mfma_f32_16x16x32_f16(ah,  BH[j][3], acc3, 0, 0, 0);
        acc3 = __builtin_amdgcn_mfma_f32_16x16x32_f16(al_, BH[j][3], acc3, 0, 0, 0);
        acc3 = __builtin_amdgcn_mfma_f32_16x16x32_f16(ah,  BL[j][3], acc3, 0, 0, 0);
    }

    // ---- C tiles -> LDS logits. C layout: col = lane&15, row = (lane>>4)*4+r ----
    {
        const int col = l & 15;
#pragma unroll
        for (int r = 0; r < 4; ++r) {
            const int t = g * 4 + r;
            smem[t * 65 + 0  + col] = acc0[r] * LSCALE2_INV;
            smem[t * 65 + 16 + col] = acc1[r] * LSCALE2_INV;
            smem[t * 65 + 32 + col] = acc2[r] * LSCALE2_INV;
            smem[t * 65 + 48 + col] = acc3[r] * LSCALE2_INV;
        }
    }
    __syncthreads();   // single wave: LDS drain

    // ---- top-2 + 2-way softmax (frozen scan): lane t handles token t ----
    float* res = smem + TPB * 65;
    if (l < TPB) {
        const float* lg = smem + l * 65;
        float m1 = -INFINITY, m2 = -INFINITY;
        int i1 = 0, i2 = 0;
        for (int e = 0; e < E_; ++e) {
            const float v = lg[e] + bias[e];
            if (v > m1)      { m2 = m1; i2 = i1; m1 = v; i1 = e; }
            else if (v > m2) { m2 = v;  i2 = e; }
        }
        const float ex  = expf(m2 - m1);
        const float den = 1.f + ex;
        res[l*4+0] = 1.f / den;
        res[l*4+1] = ex / den;
        res[l*4+2] = (float)i1;
        res[l*4+3] = (float)i2;
    }
    __syncthreads();

    // ---- output: probs (16 tokens x 64 experts = 1024 floats), float4 ----
    float* ob = out + (size_t)T0 * E_;
#pragma unroll
    for (int i = 0; i < 4; ++i) {
        const int idx = i * 256 + l * 4;
        const int t   = idx >> 6;
        const int e0  = idx & 63;
        const float p1 = res[t*4+0];
        const float p2 = res[t*4+1];
        const int   i1 = (int)res[t*4+2];
        const int   i2 = (int)res[t*4+3];
        float4 v;
        v.x = (e0+0 == i1) ? p1 : ((e0+0 == i2) ? p2 : 0.f);
        v.y = (e0+1 == i1) ? p1 : ((e0+1 == i2) ? p2 : 0.f);
        v.z = (e0+2 == i1) ? p1 : ((e0+2 == i2) ? p2 : 0.f);
        v.w = (e0+3 == i1) ? p1 : ((e0+3 == i2) ? p2 : 0.f);
        *reinterpret_cast<float4*>(ob + idx) = v;
    }
    // ids as float values (whole d_out is read as float32)
    if (l < TPB * 2) {
        out[(size_t)NTOK * E_ + (size_t)T0 * 2 + l] =
            res[(l >> 1) * 4 + 2 + (l & 1)];
    }
}

extern "C" void kernel_launch(void* const* d_in, const int* in_sizes, int n_in,
                              void* d_out, int out_size, void* d_ws, size_t ws_size,
                              hipStream_t stream) {
    const float* x = (const float*)d_in[0];
    const float* W = (const float*)d_in[1];
    const float* b = (const float*)d_in[2];
    float* out     = (float*)d_out;
    _Float16* wh   = (_Float16*)d_ws;                       // 256 KB
    _Float16* wl   = wh + (size_t)4 * NKC * 64 * 8;         // +256 KB

    hipLaunchKernelGGL(prep_w, dim3(64), dim3(256), 0, stream, W, wh, wl);
    hipLaunchKernelGGL(router_mfma, dim3(NTOK / TPB), dim3(64), 0, stream,
                       x, wh, wl, b, out);
}